// Round 9
// baseline (2946.819 us; speedup 1.0000x reference)
//
#include <hip/hip_runtime.h>

typedef unsigned short u16;
typedef __bf16  bf16x8 __attribute__((ext_vector_type(8)));
typedef float   f32x4  __attribute__((ext_vector_type(4)));
typedef unsigned short us8 __attribute__((ext_vector_type(8)));
typedef _Float16 f16x8 __attribute__((ext_vector_type(8)));
typedef float   fl4   __attribute__((ext_vector_type(4)));

#define AS1 __attribute__((address_space(1)))
#define AS3 __attribute__((address_space(3)))

__device__ __forceinline__ u16 f2bf(float f) {
    union { float f; unsigned u; } x; x.f = f;
    unsigned r = x.u + 0x7fffu + ((x.u >> 16) & 1u);
    return (u16)(r >> 16);
}

// ---------------- fp32 -> bf16 cast, 6 tensors in one dispatch ----------------
__global__ __launch_bounds__(256) void cvt6(const float* __restrict__ q,
                                            const float* __restrict__ k,
                                            const float* __restrict__ v,
                                            const float* __restrict__ Wq,
                                            const float* __restrict__ Wk,
                                            const float* __restrict__ Wv,
                                            u16* __restrict__ qb, u16* __restrict__ kb,
                                            u16* __restrict__ vb, u16* __restrict__ Wqb,
                                            u16* __restrict__ Wkb, u16* __restrict__ Wvb,
                                            int n8x, int n8w) {
    const int y = blockIdx.y;
    const float* in; u16* out; int n8;
    switch (y) {
        case 0: in = q;  out = qb;  n8 = n8x; break;
        case 1: in = k;  out = kb;  n8 = n8x; break;
        case 2: in = v;  out = vb;  n8 = n8x; break;
        case 3: in = Wq; out = Wqb; n8 = n8w; break;
        case 4: in = Wk; out = Wkb; n8 = n8w; break;
        default: in = Wv; out = Wvb; n8 = n8w; break;
    }
    int i = blockIdx.x * blockDim.x + threadIdx.x;
    int stride = gridDim.x * blockDim.x;
    for (; i < n8; i += stride) {
        const fl4* p = (const fl4*)(in + (long)i * 8);
        fl4 a = p[0], b = p[1];
        us8 o;
#pragma unroll
        for (int j = 0; j < 4; ++j) { o[j] = f2bf(a[j]); o[4 + j] = f2bf(b[j]); }
        *(us8*)(out + (long)i * 8) = o;
    }
}

// ---------------- 256x256 tile, BK=32, folded-LDS bf16 GEMM body ----------------
// Drain-all schedule (provably race-free, R5/R7 proven): stage T+1 first,
// plain-C++ ds_reads, 32 MFMA, one __syncthreads per K-tile.
// LDS: 2 buf x (A-fold [128][64] 16KB + B-fold [128][64] 16KB) = 64 KiB
//  -> 2 blocks/CU: cross-block anti-phasing hides barrier drain (R5 mechanism).
// Fold: tile row g (0..255) lives at LDS row g&127, chunk-half g>>7; with the
// XOR swizzle, physical chunk CH at row R holds logical L = CH ^ (R&7),
// logical L => tile row (L>>2)*128 + R, col8 (L&3). Staging keeps linear DMA
// dest (base + t*16) + pre-swizzled SOURCE address (both-sides rule, m201).
// mode 0: bf16 out + bias[col]; 1: bf16 out + bias[row]; 2: fp16 out * scale.
__device__ __forceinline__ void gemmk32_body(char* lds8,
                                             const u16* __restrict__ A,
                                             const u16* __restrict__ B,
                                             void* __restrict__ Cout,
                                             const float* __restrict__ bias,
                                             int mode, float scale, int NT,
                                             int lda, int ldb, int ldc,
                                             int tx, int ty) {
    const int t    = threadIdx.x;
    const int lane = t & 63;
    const int wid  = t >> 6;      // 0..7
    const int wr   = wid >> 2;    // 0..1  (128-row slice)
    const int wc   = wid & 3;     // 0..3  (64-col slice)
    const int fr   = lane & 15;
    const int kq   = lane >> 4;

    const long brow = (long)ty * 256;
    const long bcol = (long)tx * 256;

    // staging source (2 rounds each for A,B; round r: R = r*64 + t>>3)
    const int Rlo  = t >> 3;              // 0..63
    const int Lc   = (t & 7) ^ (Rlo & 7); // logical chunk (same both rounds)
    const int hRow = (Lc >> 2) * 128;     // row-half
    const int c8   = (Lc & 3) * 8;        // col element offset
    long srcA[2], srcB[2];
#pragma unroll
    for (int r = 0; r < 2; ++r) {
        srcA[r] = (brow + hRow + r * 64 + Rlo) * (long)lda + c8;
        srcB[r] = (bcol + hRow + r * 64 + Rlo) * (long)ldb + c8;
    }

    // frag read offsets: byte = R*128 + CH*16, CH = L ^ (R&7), R&7 == fr&7
    int aOff[8], bOff[4];
#pragma unroll
    for (int m = 0; m < 8; ++m) aOff[m] = (m * 16 + fr) * 128;
#pragma unroll
    for (int n = 0; n < 4; ++n) bOff[n] = 16384 + ((wc & 1) * 64 + n * 16 + fr) * 128;
    const int aCh = ((wr * 4 + kq) ^ (fr & 7)) * 16;
    const int bCh = (((wc >> 1) * 4 + kq) ^ (fr & 7)) * 16;

    f32x4 acc[8][4] = {};

    // prologue: stage tile 0, full drain
#pragma unroll
    for (int r = 0; r < 2; ++r) {
        __builtin_amdgcn_global_load_lds((const AS1 unsigned*)(A + srcA[r]),
                                         (AS3 unsigned*)(lds8 + r * 8192 + t * 16), 16, 0, 0);
        __builtin_amdgcn_global_load_lds((const AS1 unsigned*)(B + srcB[r]),
                                         (AS3 unsigned*)(lds8 + 16384 + r * 8192 + t * 16), 16, 0, 0);
    }
    __syncthreads();

    int cur = 0;
    for (int T = 0; T < NT; ++T) {
        char* bb  = lds8 + cur * 32768;
        char* bbn = lds8 + (cur ^ 1) * 32768;

        if (T + 1 < NT) {
            const long kb_ = (long)(T + 1) * 32;
#pragma unroll
            for (int r = 0; r < 2; ++r) {
                __builtin_amdgcn_global_load_lds((const AS1 unsigned*)(A + srcA[r] + kb_),
                                                 (AS3 unsigned*)(bbn + r * 8192 + t * 16), 16, 0, 0);
                __builtin_amdgcn_global_load_lds((const AS1 unsigned*)(B + srcB[r] + kb_),
                                                 (AS3 unsigned*)(bbn + 16384 + r * 8192 + t * 16), 16, 0, 0);
            }
        }

        bf16x8 af[8], bfv[4];
#pragma unroll
        for (int n = 0; n < 4; ++n) bfv[n] = *(const bf16x8*)(bb + bOff[n] + bCh);
#pragma unroll
        for (int m = 0; m < 8; ++m) af[m] = *(const bf16x8*)(bb + aOff[m] + aCh);

        __builtin_amdgcn_s_setprio(1);
#pragma unroll
        for (int m = 0; m < 8; ++m)
#pragma unroll
            for (int n = 0; n < 4; ++n)
                acc[m][n] = __builtin_amdgcn_mfma_f32_16x16x32_bf16(af[m], bfv[n], acc[m][n], 0, 0, 0);
        __builtin_amdgcn_s_setprio(0);

        __syncthreads();
        cur ^= 1;
    }

    // epilogue: C/D layout col=lane&15, row=(lane>>4)*4+j; runtime mode (uniform)
    const long crow = brow + wr * 128;
    const long ccol = bcol + wc * 64;
#pragma unroll
    for (int m = 0; m < 8; ++m) {
#pragma unroll
        for (int n = 0; n < 4; ++n) {
#pragma unroll
            for (int j = 0; j < 4; ++j) {
                long r = crow + m * 16 + kq * 4 + j;
                long c = ccol + n * 16 + fr;
                float vv = acc[m][n][j];
                if (mode == 0)      { vv += bias[c]; ((u16*)Cout)[r * (long)ldc + c] = f2bf(vv); }
                else if (mode == 1) { vv += bias[r]; ((u16*)Cout)[r * (long)ldc + c] = f2bf(vv); }
                else                { ((_Float16*)Cout)[r * (long)ldc + c] = (_Float16)(vv * scale); }
            }
        }
    }
}

// ---------------- all 3 projections in ONE dispatch ----------------
__global__ __launch_bounds__(512, 4) void proj3(const u16* __restrict__ qb,
                                                const u16* __restrict__ kb,
                                                const u16* __restrict__ vb,
                                                const u16* __restrict__ Wqb,
                                                const u16* __restrict__ Wkb,
                                                const u16* __restrict__ Wvb,
                                                u16* __restrict__ pq, u16* __restrict__ pk,
                                                u16* __restrict__ pvT,
                                                const float* __restrict__ bq,
                                                const float* __restrict__ bk,
                                                const float* __restrict__ bv,
                                                int E, int NBL) {
    __shared__ alignas(16) char lds8[65536];
    const int bx  = blockIdx.x;                 // 0..255
    const int swz = (bx & 7) * 32 + (bx >> 3);  // XCD-bijective (256 % 8 == 0)
    const int y   = blockIdx.y;
    if (y < 2) {
        // pq/pk = x @ W^T + b[col]:  M=16384 (ty 0..63), N=1024 (tx 0..3)
        const int tx = swz & 3, ty = swz >> 2;
        gemmk32_body(lds8, y == 0 ? qb : kb, y == 0 ? Wqb : Wkb,
                     y == 0 ? (void*)pq : (void*)pk, y == 0 ? bq : bk,
                     0, 1.f, E / 32, E, E, E, tx, ty);
    } else {
        // pvT = Wv @ v^T + bv[row]:  M=1024 (ty 0..3), N=16384 (tx 0..63)
        const int tx = swz & 63, ty = swz >> 6;
        gemmk32_body(lds8, Wvb, vb, (void*)pvT, bv, 1, 1.f, E / 32, E, E, NBL, tx, ty);
    }
}

// ---------------- S = pq @ pk^T * scale -> fp16, z = batch ----------------
__global__ __launch_bounds__(512, 4) void s_gemm(const u16* __restrict__ pq,
                                                 const u16* __restrict__ pk,
                                                 u16* __restrict__ S,
                                                 float scale, int E, int L) {
    __shared__ alignas(16) char lds8[65536];
    const int wg  = blockIdx.y * gridDim.x + blockIdx.x;   // 0..255
    const int swz = (wg & 7) * 32 + (wg >> 3);
    const int tx = swz & 15, ty = swz >> 4;
    const long zo = blockIdx.z;
    gemmk32_body(lds8, pq + zo * L * E, pk + zo * L * E,
                 (void*)(S + zo * (long)L * L), nullptr, 2, scale,
                 E / 32, E, E, L, tx, ty);
}

// ---------------- 256x256 BK=64 GEMM (R7 proven) — PV path ----------------
template <int MODE>
__global__ __launch_bounds__(512, 2) void gemm256d(const u16* __restrict__ A,
                                                   const u16* __restrict__ B,
                                                   void* __restrict__ Cout,
                                                   const float* __restrict__ bias,
                                                   float scale, int K,
                                                   int lda, int ldb, int ldc,
                                                   long sAz, long sBz, long sCz) {
    __shared__ alignas(16) char lds8[2 * 65536];

    const int t    = threadIdx.x;
    const int lane = t & 63;
    const int wid  = t >> 6;
    const int wr   = wid >> 2;
    const int wc   = wid & 3;
    const int fr   = lane & 15;
    const int kq   = lane >> 4;

    const int gx  = gridDim.x;
    const int nwg = gx * gridDim.y;
    const int wg  = blockIdx.y * gx + blockIdx.x;
    const int swz = (wg & 7) * (nwg >> 3) + (wg >> 3);
    const long brow = (long)(swz / gx) * 256;
    const long bcol = (long)(swz % gx) * 256;

    const u16* Az = A + sAz * blockIdx.z;
    const u16* Bz = B + sBz * blockIdx.z;

    const int trow = t >> 3;
    const int tc8  = ((t & 7) ^ (trow & 7)) * 8;
    long offA[4], offB[4];
#pragma unroll
    for (int r = 0; r < 4; ++r) offA[r] = (brow + r * 64 + trow) * (long)lda + tc8;
#pragma unroll
    for (int r = 0; r < 4; ++r) offB[r] = (bcol + r * 64 + trow) * (long)ldb + tc8;

    int aRow[8], bRow[4], aCh[2];
#pragma unroll
    for (int m = 0; m < 8; ++m) aRow[m] = (wr * 128 + m * 16 + fr) * 128;
#pragma unroll
    for (int n = 0; n < 4; ++n) bRow[n] = 32768 + (wc * 64 + n * 16 + fr) * 128;
#pragma unroll
    for (int ks = 0; ks < 2; ++ks) aCh[ks] = (((ks << 2) | kq) ^ (fr & 7)) * 16;

    const int NT = K >> 6;
    f32x4 acc[8][4] = {};

    {
        char* bb0 = lds8;
#pragma unroll
        for (int r = 0; r < 4; ++r)
            __builtin_amdgcn_global_load_lds((const AS1 unsigned*)(Az + offA[r]),
                                             (AS3 unsigned*)(bb0 + r * 8192 + t * 16), 16, 0, 0);
#pragma unroll
        for (int r = 0; r < 4; ++r)
            __builtin_amdgcn_global_load_lds((const AS1 unsigned*)(Bz + offB[r]),
                                             (AS3 unsigned*)(bb0 + 32768 + r * 8192 + t * 16), 16, 0, 0);
    }
    __syncthreads();

    int cur = 0;
    for (int T = 0; T < NT; ++T) {
        char* bb  = lds8 + cur * 65536;
        char* bbn = lds8 + (cur ^ 1) * 65536;

        if (T + 1 < NT) {
            const long kcol = (long)(T + 1) << 6;
#pragma unroll
            for (int r = 0; r < 4; ++r)
                __builtin_amdgcn_global_load_lds((const AS1 unsigned*)(Az + offA[r] + kcol),
                                                 (AS3 unsigned*)(bbn + r * 8192 + t * 16), 16, 0, 0);
#pragma unroll
            for (int r = 0; r < 4; ++r)
                __builtin_amdgcn_global_load_lds((const AS1 unsigned*)(Bz + offB[r] + kcol),
                                                 (AS3 unsigned*)(bbn + 32768 + r * 8192 + t * 16), 16, 0, 0);
        }

        bf16x8 bfv[2][4], afl[2][4], afh[2][4];
#pragma unroll
        for (int ks = 0; ks < 2; ++ks)
#pragma unroll
            for (int n = 0; n < 4; ++n)
                bfv[ks][n] = *(const bf16x8*)(bb + bRow[n] + aCh[ks]);
#pragma unroll
        for (int ks = 0; ks < 2; ++ks)
#pragma unroll
            for (int m = 0; m < 4; ++m)
                afl[ks][m] = *(const bf16x8*)(bb + aRow[m] + aCh[ks]);

        __builtin_amdgcn_s_setprio(1);
#pragma unroll
        for (int ks = 0; ks < 2; ++ks)
#pragma unroll
            for (int m = 0; m < 4; ++m)
#pragma unroll
                for (int n = 0; n < 4; ++n)
                    acc[m][n] = __builtin_amdgcn_mfma_f32_16x16x32_bf16(afl[ks][m], bfv[ks][n], acc[m][n], 0, 0, 0);
        __builtin_amdgcn_s_setprio(0);

#pragma unroll
        for (int ks = 0; ks < 2; ++ks)
#pragma unroll
            for (int m = 0; m < 4; ++m)
                afh[ks][m] = *(const bf16x8*)(bb + aRow[4 + m] + aCh[ks]);

        __builtin_amdgcn_s_setprio(1);
#pragma unroll
        for (int ks = 0; ks < 2; ++ks)
#pragma unroll
            for (int m = 0; m < 4; ++m)
#pragma unroll
                for (int n = 0; n < 4; ++n)
                    acc[4 + m][n] = __builtin_amdgcn_mfma_f32_16x16x32_bf16(afh[ks][m], bfv[ks][n], acc[4 + m][n], 0, 0, 0);
        __builtin_amdgcn_s_setprio(0);

        __syncthreads();
        cur ^= 1;
    }

    const long crow = brow + wr * 128;
    const long ccol = bcol + wc * 64;
    const long cz = sCz * blockIdx.z;
#pragma unroll
    for (int m = 0; m < 8; ++m) {
#pragma unroll
        for (int n = 0; n < 4; ++n) {
#pragma unroll
            for (int j = 0; j < 4; ++j) {
                long r = crow + m * 16 + kq * 4 + j;
                long c = ccol + n * 16 + fr;
                float vv = acc[m][n][j];
                if (MODE == 0)      { vv += bias[c]; ((u16*)Cout)[cz + r * ldc + c] = f2bf(vv); }
                else if (MODE == 1) { vv += bias[r]; ((u16*)Cout)[cz + r * ldc + c] = f2bf(vv); }
                else if (MODE == 2) { ((_Float16*)Cout)[cz + r * ldc + c] = (_Float16)(vv * scale); }
                else                { ((float*)Cout)[cz + r * ldc + c] = vv; }
            }
        }
    }
}

// ---------------- row softmax: fp16 in -> bf16 out, in place, L=4096 ----------------
__global__ __launch_bounds__(256) void softmax_row(u16* __restrict__ S, int L) {
    const long row = blockIdx.x;
    u16* rp = S + row * L;
    const int t = threadIdx.x;
    const int lane = t & 63, wid = t >> 6;

    f16x8 h0 = *(const f16x8*)(rp + t * 16);
    f16x8 h1 = *(const f16x8*)(rp + t * 16 + 8);
    float x[16];
#pragma unroll
    for (int j = 0; j < 8; ++j) { x[j] = (float)h0[j]; x[8 + j] = (float)h1[j]; }

    float m = -1e30f;
#pragma unroll
    for (int j = 0; j < 16; ++j) m = fmaxf(m, x[j]);
#pragma unroll
    for (int o = 32; o; o >>= 1) m = fmaxf(m, __shfl_xor(m, o));

    __shared__ float redmax[4], redsum[4];
    if (lane == 0) redmax[wid] = m;
    __syncthreads();
    m = fmaxf(fmaxf(redmax[0], redmax[1]), fmaxf(redmax[2], redmax[3]));

    float e[16], s = 0.f;
#pragma unroll
    for (int j = 0; j < 16; ++j) { e[j] = __expf(x[j] - m); s += e[j]; }
#pragma unroll
    for (int o = 32; o; o >>= 1) s += __shfl_xor(s, o);
    if (lane == 0) redsum[wid] = s;
    __syncthreads();
    s = redsum[0] + redsum[1] + redsum[2] + redsum[3];
    float inv = 1.f / s;

    us8 o0, o1;
#pragma unroll
    for (int j = 0; j < 8; ++j) { o0[j] = f2bf(e[j] * inv); o1[j] = f2bf(e[8 + j] * inv); }
    *(us8*)(rp + t * 16) = o0;
    *(us8*)(rp + t * 16 + 8) = o1;
}

extern "C" void kernel_launch(void* const* d_in, const int* in_sizes, int n_in,
                              void* d_out, int out_size, void* d_ws, size_t ws_size,
                              hipStream_t stream) {
    (void)in_sizes; (void)n_in; (void)out_size;
    const float* q  = (const float*)d_in[0];
    const float* k  = (const float*)d_in[1];
    const float* v  = (const float*)d_in[2];
    const float* Wq = (const float*)d_in[3];
    const float* bq = (const float*)d_in[4];
    const float* Wk = (const float*)d_in[5];
    const float* bk = (const float*)d_in[6];
    const float* Wv = (const float*)d_in[7];
    const float* bv = (const float*)d_in[8];
    float* out = (float*)d_out;

    constexpr long MB = 1l << 20;
    char* ws = (char*)d_ws;
    u16* pq  = (u16*)(ws + 0 * MB);     // 32 MB  [16384,1024] bf16
    u16* pk  = (u16*)(ws + 32 * MB);    // 32 MB
    u16* pvT = (u16*)(ws + 64 * MB);    // 32 MB  [1024,16384] bf16
    u16* Wqb = (u16*)(ws + 96 * MB);    // 2 MB
    u16* Wkb = (u16*)(ws + 98 * MB);    // 2 MB
    u16* Wvb = (u16*)(ws + 100 * MB);   // 2 MB
    u16* qb  = (u16*)(ws + 104 * MB);   // 32 MB (dead after projections)
    u16* kb  = (u16*)(ws + 136 * MB);   // 32 MB
    u16* vb  = (u16*)(ws + 168 * MB);   // 32 MB
    u16* S4  = (u16*)(ws + 104 * MB);   // z4: 128 MB, aliases qb/kb/vb (dead)

    const int L = 4096, E = 1024, NB = 4;
    const int n8_x = (NB * L * E) / 8;
    const int n8_w = (E * E) / 8;
    const bool z4 = ws_size >= (size_t)233 * MB;

    cvt6<<<dim3(1024, 6), 256, 0, stream>>>(q, k, v, Wq, Wk, Wv,
                                            qb, kb, vb, Wqb, Wkb, Wvb, n8_x, n8_w);

    // all three projections in one dispatch: 768 blocks, 2 blocks/CU
    proj3<<<dim3(256, 3), 512, 0, stream>>>(qb, kb, vb, Wqb, Wkb, Wvb,
                                            pq, pk, pvT, bq, bk, bv, E, NB * L);

    const float scale = 0.03125f;  // 1/sqrt(1024)
    if (z4) {
        // S (fp16), all 4 batches: 1024 blocks, 2/CU
        s_gemm<<<dim3(16, 16, 4), 512, 0, stream>>>(pq, pk, S4, scale, E, L);
        softmax_row<<<NB * L, 256, 0, stream>>>(S4, L);
        // PV: out = attn @ pvT^T (BK=64 path, 256 blocks)
        gemm256d<3><<<dim3(4, 16, 4), 512, 0, stream>>>(S4, pvT, out,
                                                        nullptr, 1.f, L, L, NB * L, E,
                                                        (long)L * L, (long)L, (long)L * E);
    } else {
        u16* S2 = S4;  // 64 MB, 2 batches at a time
        for (int p = 0; p < 2; ++p) {
            const long zb = p * 2;
            s_gemm<<<dim3(16, 16, 2), 512, 0, stream>>>(pq + zb * L * E, pk + zb * L * E,
                                                        S2, scale, E, L);
            softmax_row<<<2 * L, 256, 0, stream>>>(S2, L);
            gemm256d<3><<<dim3(4, 16, 2), 512, 0, stream>>>(S2, pvT + zb * L, out + zb * L * E,
                                                            nullptr, 1.f, L, L, NB * L, E,
                                                            (long)L * L, (long)L, (long)L * E);
        }
    }
}

// Round 10
// 443.875 us; speedup vs baseline: 6.6388x; 6.6388x over previous
//
#include <hip/hip_runtime.h>

typedef unsigned short u16;
typedef __bf16  bf16x8 __attribute__((ext_vector_type(8)));
typedef float   f32x4  __attribute__((ext_vector_type(4)));
typedef unsigned short us8 __attribute__((ext_vector_type(8)));
typedef _Float16 f16x8 __attribute__((ext_vector_type(8)));
typedef float   fl4   __attribute__((ext_vector_type(4)));

#define AS1 __attribute__((address_space(1)))
#define AS3 __attribute__((address_space(3)))

__device__ __forceinline__ u16 f2bf(float f) {
    union { float f; unsigned u; } x; x.f = f;
    unsigned r = x.u + 0x7fffu + ((x.u >> 16) & 1u);
    return (u16)(r >> 16);
}

// ---------------- fp32 -> bf16 cast, 6 tensors in one dispatch ----------------
__global__ __launch_bounds__(256) void cvt6(const float* __restrict__ q,
                                            const float* __restrict__ k,
                                            const float* __restrict__ v,
                                            const float* __restrict__ Wq,
                                            const float* __restrict__ Wk,
                                            const float* __restrict__ Wv,
                                            u16* __restrict__ qb, u16* __restrict__ kb,
                                            u16* __restrict__ vb, u16* __restrict__ Wqb,
                                            u16* __restrict__ Wkb, u16* __restrict__ Wvb,
                                            int n8x, int n8w) {
    const int y = blockIdx.y;
    const float* in; u16* out; int n8;
    switch (y) {
        case 0: in = q;  out = qb;  n8 = n8x; break;
        case 1: in = k;  out = kb;  n8 = n8x; break;
        case 2: in = v;  out = vb;  n8 = n8x; break;
        case 3: in = Wq; out = Wqb; n8 = n8w; break;
        case 4: in = Wk; out = Wkb; n8 = n8w; break;
        default: in = Wv; out = Wvb; n8 = n8w; break;
    }
    int i = blockIdx.x * blockDim.x + threadIdx.x;
    int stride = gridDim.x * blockDim.x;
    for (; i < n8; i += stride) {
        const fl4* p = (const fl4*)(in + (long)i * 8);
        fl4 a = p[0], b = p[1];
        us8 o;
#pragma unroll
        for (int j = 0; j < 4; ++j) { o[j] = f2bf(a[j]); o[4 + j] = f2bf(b[j]); }
        *(us8*)(out + (long)i * 8) = o;
    }
}

// ---------------- 256x256 tile bf16 GEMM, C = A * B^T (R8 proven base) ----------------
// Drain-all schedule (provably race-free): stage T+1 first, plain-C++ ds_reads,
// MFMA, one __syncthreads per K-tile. NO setprio / no explicit waitcnt pins:
// the compiler's scoreboard emits counted lgkmcnt and interleaves the A-hi
// ds_reads under the half-0 MFMA cluster (m97), overlapping LDS and matrix
// pipes that previously ran serially (R8: 5212 cyc/tile = LDS 2800 + MFMA 2480).
// MODE 0: bf16 out + bias[col]; MODE 1: bf16 out + bias[row];
// MODE 2: fp16 out * scale;     MODE 3: fp32 out.
template <int MODE>
__global__ __launch_bounds__(512, 2) void gemm256d(const u16* __restrict__ A,
                                                   const u16* __restrict__ B,
                                                   void* __restrict__ Cout,
                                                   const float* __restrict__ bias,
                                                   float scale, int K,
                                                   int lda, int ldb, int ldc,
                                                   long sAz, long sBz, long sCz) {
    __shared__ alignas(16) char lds8[2 * 65536];

    const int t    = threadIdx.x;
    const int lane = t & 63;
    const int wid  = t >> 6;
    const int wr   = wid >> 2;    // 0..1
    const int wc   = wid & 3;     // 0..3
    const int fr   = lane & 15;
    const int kq   = lane >> 4;

    const int gx  = gridDim.x;
    const int nwg = gx * gridDim.y;
    const int wg  = blockIdx.y * gx + blockIdx.x;
    const int swz = (wg & 7) * (nwg >> 3) + (wg >> 3);
    const long brow = (long)(swz / gx) * 256;
    const long bcol = (long)(swz % gx) * 256;

    const u16* Az = A + sAz * blockIdx.z;
    const u16* Bz = B + sBz * blockIdx.z;

    const int trow = t >> 3;
    const int tc8  = ((t & 7) ^ (trow & 7)) * 8;
    long offA[4], offB[4];
#pragma unroll
    for (int r = 0; r < 4; ++r) offA[r] = (brow + r * 64 + trow) * (long)lda + tc8;
#pragma unroll
    for (int r = 0; r < 4; ++r) offB[r] = (bcol + r * 64 + trow) * (long)ldb + tc8;

    int aRow[8], bRow[4], aCh[2];
#pragma unroll
    for (int m = 0; m < 8; ++m) aRow[m] = (wr * 128 + m * 16 + fr) * 128;
#pragma unroll
    for (int n = 0; n < 4; ++n) bRow[n] = 32768 + (wc * 64 + n * 16 + fr) * 128;
#pragma unroll
    for (int ks = 0; ks < 2; ++ks) aCh[ks] = (((ks << 2) | kq) ^ (fr & 7)) * 16;

    const int NT = K >> 6;
    f32x4 acc[8][4] = {};

    {
        char* bb0 = lds8;
#pragma unroll
        for (int r = 0; r < 4; ++r)
            __builtin_amdgcn_global_load_lds((const AS1 unsigned*)(Az + offA[r]),
                                             (AS3 unsigned*)(bb0 + r * 8192 + t * 16), 16, 0, 0);
#pragma unroll
        for (int r = 0; r < 4; ++r)
            __builtin_amdgcn_global_load_lds((const AS1 unsigned*)(Bz + offB[r]),
                                             (AS3 unsigned*)(bb0 + 32768 + r * 8192 + t * 16), 16, 0, 0);
    }
    __syncthreads();

    int cur = 0;
    for (int T = 0; T < NT; ++T) {
        char* bb  = lds8 + cur * 65536;
        char* bbn = lds8 + (cur ^ 1) * 65536;

        if (T + 1 < NT) {
            const long kcol = (long)(T + 1) << 6;
#pragma unroll
            for (int r = 0; r < 4; ++r)
                __builtin_amdgcn_global_load_lds((const AS1 unsigned*)(Az + offA[r] + kcol),
                                                 (AS3 unsigned*)(bbn + r * 8192 + t * 16), 16, 0, 0);
#pragma unroll
            for (int r = 0; r < 4; ++r)
                __builtin_amdgcn_global_load_lds((const AS1 unsigned*)(Bz + offB[r] + kcol),
                                                 (AS3 unsigned*)(bbn + 32768 + r * 8192 + t * 16), 16, 0, 0);
        }

        // m-half 0: B(all) + A(m0..3); no setprio / no pins -> scheduler can
        // pull the A(m4..7) reads below into this MFMA cluster.
        bf16x8 bfv[2][4], afl[2][4], afh[2][4];
#pragma unroll
        for (int ks = 0; ks < 2; ++ks)
#pragma unroll
            for (int n = 0; n < 4; ++n)
                bfv[ks][n] = *(const bf16x8*)(bb + bRow[n] + aCh[ks]);
#pragma unroll
        for (int ks = 0; ks < 2; ++ks)
#pragma unroll
            for (int m = 0; m < 4; ++m)
                afl[ks][m] = *(const bf16x8*)(bb + aRow[m] + aCh[ks]);

#pragma unroll
        for (int ks = 0; ks < 2; ++ks)
#pragma unroll
            for (int m = 0; m < 4; ++m)
#pragma unroll
                for (int n = 0; n < 4; ++n)
                    acc[m][n] = __builtin_amdgcn_mfma_f32_16x16x32_bf16(afl[ks][m], bfv[ks][n], acc[m][n], 0, 0, 0);

        // m-half 1: A(m4..7), B reused
#pragma unroll
        for (int ks = 0; ks < 2; ++ks)
#pragma unroll
            for (int m = 0; m < 4; ++m)
                afh[ks][m] = *(const bf16x8*)(bb + aRow[4 + m] + aCh[ks]);

#pragma unroll
        for (int ks = 0; ks < 2; ++ks)
#pragma unroll
            for (int m = 0; m < 4; ++m)
#pragma unroll
                for (int n = 0; n < 4; ++n)
                    acc[4 + m][n] = __builtin_amdgcn_mfma_f32_16x16x32_bf16(afh[ks][m], bfv[ks][n], acc[4 + m][n], 0, 0, 0);

        __syncthreads();
        cur ^= 1;
    }

    const long crow = brow + wr * 128;
    const long ccol = bcol + wc * 64;
    const long cz = sCz * blockIdx.z;
#pragma unroll
    for (int m = 0; m < 8; ++m) {
#pragma unroll
        for (int n = 0; n < 4; ++n) {
#pragma unroll
            for (int j = 0; j < 4; ++j) {
                long r = crow + m * 16 + kq * 4 + j;
                long c = ccol + n * 16 + fr;
                float vv = acc[m][n][j];
                if (MODE == 0)      { vv += bias[c]; ((u16*)Cout)[cz + r * ldc + c] = f2bf(vv); }
                else if (MODE == 1) { vv += bias[r]; ((u16*)Cout)[cz + r * ldc + c] = f2bf(vv); }
                else if (MODE == 2) { ((_Float16*)Cout)[cz + r * ldc + c] = (_Float16)(vv * scale); }
                else                { ((float*)Cout)[cz + r * ldc + c] = vv; }
            }
        }
    }
}

// ---------------- 128x128 tile bf16 GEMM (R5 proven — fallback path) ----------------
template <int MODE>
__global__ __launch_bounds__(256, 2) void gemm128(const u16* __restrict__ A,
                                                  const u16* __restrict__ B,
                                                  void* __restrict__ Cout,
                                                  const float* __restrict__ bias,
                                                  float scale, int K,
                                                  int lda, int ldb, int ldc,
                                                  long sAz, long sBz, long sCz) {
    __shared__ alignas(16) char lds8[2 * 32768];

    const int t    = threadIdx.x;
    const int lane = t & 63;
    const int wid  = t >> 6;
    const int wr   = wid >> 1;
    const int wc   = wid & 1;
    const int fr   = lane & 15;
    const int kq   = lane >> 4;

    const int gx  = gridDim.x;
    const int nwg = gx * gridDim.y;
    const int wg  = blockIdx.y * gx + blockIdx.x;
    const int swz = (wg & 7) * (nwg >> 3) + (wg >> 3);
    const long brow = (long)(swz / gx) * 128;
    const long bcol = (long)(swz % gx) * 128;

    const u16* Az = A + sAz * blockIdx.z;
    const u16* Bz = B + sBz * blockIdx.z;

    const int trow = t >> 3;
    const int tc8  = ((t & 7) ^ (trow & 7)) * 8;
    long offA[4], offB[4];
#pragma unroll
    for (int r = 0; r < 4; ++r) offA[r] = (brow + r * 32 + trow) * (long)lda + tc8;
#pragma unroll
    for (int r = 0; r < 4; ++r) offB[r] = (bcol + r * 32 + trow) * (long)ldb + tc8;

    int aRow[4], bRow[4], aCh[2];
#pragma unroll
    for (int m = 0; m < 4; ++m) aRow[m] = (wr * 64 + m * 16 + fr) * 128;
#pragma unroll
    for (int n = 0; n < 4; ++n) bRow[n] = 16384 + (wc * 64 + n * 16 + fr) * 128;
#pragma unroll
    for (int ks = 0; ks < 2; ++ks) aCh[ks] = (((ks << 2) | kq) ^ (fr & 7)) * 16;

    const int NT = K >> 6;
    f32x4 acc[4][4] = {};

    {
        char* bb0 = lds8;
#pragma unroll
        for (int r = 0; r < 4; ++r)
            __builtin_amdgcn_global_load_lds((const AS1 unsigned*)(Az + offA[r]),
                                             (AS3 unsigned*)(bb0 + r * 4096 + t * 16), 16, 0, 0);
#pragma unroll
        for (int r = 0; r < 4; ++r)
            __builtin_amdgcn_global_load_lds((const AS1 unsigned*)(Bz + offB[r]),
                                             (AS3 unsigned*)(bb0 + 16384 + r * 4096 + t * 16), 16, 0, 0);
    }
    __syncthreads();

    int cur = 0;
    for (int T = 0; T < NT; ++T) {
        char* bb  = lds8 + cur * 32768;
        char* bbn = lds8 + (cur ^ 1) * 32768;

        if (T + 1 < NT) {
            const long kcol = (long)(T + 1) << 6;
#pragma unroll
            for (int r = 0; r < 4; ++r)
                __builtin_amdgcn_global_load_lds((const AS1 unsigned*)(Az + offA[r] + kcol),
                                                 (AS3 unsigned*)(bbn + r * 4096 + t * 16), 16, 0, 0);
#pragma unroll
            for (int r = 0; r < 4; ++r)
                __builtin_amdgcn_global_load_lds((const AS1 unsigned*)(Bz + offB[r] + kcol),
                                                 (AS3 unsigned*)(bbn + 16384 + r * 4096 + t * 16), 16, 0, 0);
        }

        bf16x8 af[2][4], bfv[2][4];
#pragma unroll
        for (int ks = 0; ks < 2; ++ks)
#pragma unroll
            for (int m = 0; m < 4; ++m)
                af[ks][m] = *(const bf16x8*)(bb + aRow[m] + aCh[ks]);
#pragma unroll
        for (int ks = 0; ks < 2; ++ks)
#pragma unroll
            for (int n = 0; n < 4; ++n)
                bfv[ks][n] = *(const bf16x8*)(bb + bRow[n] + aCh[ks]);

#pragma unroll
        for (int ks = 0; ks < 2; ++ks)
#pragma unroll
            for (int m = 0; m < 4; ++m)
#pragma unroll
                for (int n = 0; n < 4; ++n)
                    acc[m][n] = __builtin_amdgcn_mfma_f32_16x16x32_bf16(af[ks][m], bfv[ks][n], acc[m][n], 0, 0, 0);

        __syncthreads();
        cur ^= 1;
    }

    const long crow = brow + wr * 64;
    const long ccol = bcol + wc * 64;
    const long cz = sCz * blockIdx.z;
#pragma unroll
    for (int m = 0; m < 4; ++m) {
#pragma unroll
        for (int n = 0; n < 4; ++n) {
#pragma unroll
            for (int j = 0; j < 4; ++j) {
                long r = crow + m * 16 + kq * 4 + j;
                long c = ccol + n * 16 + fr;
                float vv = acc[m][n][j];
                if (MODE == 0)      { vv += bias[c]; ((u16*)Cout)[cz + r * ldc + c] = f2bf(vv); }
                else if (MODE == 1) { vv += bias[r]; ((u16*)Cout)[cz + r * ldc + c] = f2bf(vv); }
                else if (MODE == 2) { ((_Float16*)Cout)[cz + r * ldc + c] = (_Float16)(vv * scale); }
                else                { ((float*)Cout)[cz + r * ldc + c] = vv; }
            }
        }
    }
}

// ---------------- row softmax: fp16 in -> bf16 out, in place, L=4096 ----------------
__global__ __launch_bounds__(256) void softmax_row(u16* __restrict__ S, int L) {
    const long row = blockIdx.x;
    u16* rp = S + row * L;
    const int t = threadIdx.x;
    const int lane = t & 63, wid = t >> 6;

    f16x8 h0 = *(const f16x8*)(rp + t * 16);
    f16x8 h1 = *(const f16x8*)(rp + t * 16 + 8);
    float x[16];
#pragma unroll
    for (int j = 0; j < 8; ++j) { x[j] = (float)h0[j]; x[8 + j] = (float)h1[j]; }

    float m = -1e30f;
#pragma unroll
    for (int j = 0; j < 16; ++j) m = fmaxf(m, x[j]);
#pragma unroll
    for (int o = 32; o; o >>= 1) m = fmaxf(m, __shfl_xor(m, o));

    __shared__ float redmax[4], redsum[4];
    if (lane == 0) redmax[wid] = m;
    __syncthreads();
    m = fmaxf(fmaxf(redmax[0], redmax[1]), fmaxf(redmax[2], redmax[3]));

    float e[16], s = 0.f;
#pragma unroll
    for (int j = 0; j < 16; ++j) { e[j] = __expf(x[j] - m); s += e[j]; }
#pragma unroll
    for (int o = 32; o; o >>= 1) s += __shfl_xor(s, o);
    if (lane == 0) redsum[wid] = s;
    __syncthreads();
    s = redsum[0] + redsum[1] + redsum[2] + redsum[3];
    float inv = 1.f / s;

    us8 o0, o1;
#pragma unroll
    for (int j = 0; j < 8; ++j) { o0[j] = f2bf(e[j] * inv); o1[j] = f2bf(e[8 + j] * inv); }
    *(us8*)(rp + t * 16) = o0;
    *(us8*)(rp + t * 16 + 8) = o1;
}

extern "C" void kernel_launch(void* const* d_in, const int* in_sizes, int n_in,
                              void* d_out, int out_size, void* d_ws, size_t ws_size,
                              hipStream_t stream) {
    (void)in_sizes; (void)n_in; (void)out_size;
    const float* q  = (const float*)d_in[0];
    const float* k  = (const float*)d_in[1];
    const float* v  = (const float*)d_in[2];
    const float* Wq = (const float*)d_in[3];
    const float* bq = (const float*)d_in[4];
    const float* Wk = (const float*)d_in[5];
    const float* bk = (const float*)d_in[6];
    const float* Wv = (const float*)d_in[7];
    const float* bv = (const float*)d_in[8];
    float* out = (float*)d_out;

    constexpr long MB = 1l << 20;
    char* ws = (char*)d_ws;
    u16* pq  = (u16*)(ws + 0 * MB);     // 32 MB  [16384,1024] bf16
    u16* pk  = (u16*)(ws + 32 * MB);    // 32 MB
    u16* pvT = (u16*)(ws + 64 * MB);    // 32 MB  [1024,16384] bf16
    u16* Wqb = (u16*)(ws + 96 * MB);    // 2 MB
    u16* Wkb = (u16*)(ws + 98 * MB);    // 2 MB
    u16* Wvb = (u16*)(ws + 100 * MB);   // 2 MB
    u16* qb  = (u16*)(ws + 104 * MB);   // 32 MB (dead after projections)
    u16* kb  = (u16*)(ws + 136 * MB);   // 32 MB
    u16* vb  = (u16*)(ws + 168 * MB);   // 32 MB
    u16* S4  = (u16*)(ws + 104 * MB);   // z4: 128 MB, aliases qb/kb/vb (dead)

    const int L = 4096, E = 1024, NB = 4;
    const int n8_x = (NB * L * E) / 8;
    const int n8_w = (E * E) / 8;
    const bool z4 = ws_size >= (size_t)233 * MB;

    cvt6<<<dim3(1024, 6), 256, 0, stream>>>(q, k, v, Wq, Wk, Wv,
                                            qb, kb, vb, Wqb, Wkb, Wvb, n8_x, n8_w);

    // projections: pq = q@Wq^T + bq   (M=16384 -> gy=64, N=1024 -> gx=4) 256 blocks
    dim3 gproj(4, 64, 1);
    gemm256d<0><<<gproj, 512, 0, stream>>>(qb, Wqb, pq, bq, 1.f, E, E, E, E, 0, 0, 0);
    gemm256d<0><<<gproj, 512, 0, stream>>>(kb, Wkb, pk, bk, 1.f, E, E, E, E, 0, 0, 0);
    // pvT = Wv @ v^T + bv[row]   (M=1024 -> gy=4, N=16384 -> gx=64) 256 blocks
    dim3 gpv(64, 4, 1);
    gemm256d<1><<<gpv, 512, 0, stream>>>(Wvb, vb, pvT, bv, 1.f, E, E, E, NB * L, 0, 0, 0);

    const float scale = 0.03125f;  // 1/sqrt(1024)
    if (z4) {
        // S (fp16), all 4 batches: 1024 blocks
        gemm256d<2><<<dim3(16, 16, 4), 512, 0, stream>>>(pq, pk, S4, nullptr, scale, E, E, E, L,
                                                         (long)L * E, (long)L * E, (long)L * L);
        softmax_row<<<NB * L, 256, 0, stream>>>(S4, L);
        // PV: out = attn @ pvT^T (256 blocks)
        gemm256d<3><<<dim3(4, 16, 4), 512, 0, stream>>>(S4, pvT, out,
                                                        nullptr, 1.f, L, L, NB * L, E,
                                                        (long)L * L, (long)L, (long)L * E);
    } else {
        u16* S2 = S4;  // 64 MB, 2 batches at a time
        for (int p = 0; p < 2; ++p) {
            const long zb = p * 2;
            gemm256d<2><<<dim3(16, 16, 2), 512, 0, stream>>>(pq + zb * L * E, pk + zb * L * E,
                                                             S2, nullptr, scale, E, E, E, L,
                                                             (long)L * E, (long)L * E, (long)L * L);
            softmax_row<<<2 * L, 256, 0, stream>>>(S2, L);
            gemm256d<3><<<dim3(4, 16, 2), 512, 0, stream>>>(S2, pvT + zb * L, out + zb * L * E,
                                                            nullptr, 1.f, L, L, NB * L, E,
                                                            (long)L * L, (long)L, (long)L * E);
        }
    }
}